// Round 5
// baseline (756.104 us; speedup 1.0000x reference)
//
#include <hip/hip_runtime.h>
#include <hip/hip_bf16.h>

// db4 analysis filters (DEC_LO, DEC_HI[k] = (-1)^(k+1) DEC_LO[7-k])
#define DL_INIT {-0.010597401784997278f, 0.032883011666982945f, 0.030841381835986965f, \
  -0.18703481171888114f, -0.02798376941698385f, 0.6308807679295904f, \
  0.7148465705525415f, 0.23037781330885523f}
#define DH_INIT {-0.23037781330885523f, 0.7148465705525415f, -0.6308807679295904f, \
  -0.02798376941698385f, 0.18703481171888114f, 0.030841381835986965f, \
  -0.032883011666982945f, -0.010597401784997278f}

// Sizes: B=32, C=64, S=64, M=35 -> P=1225 px per subband plane.
// Padded pitch SP=1232 (64B rows). PLANE = 2048*1232.
#define SP 1232
#define PLANE 2523136

// ---------------- fc0 ----------------
__global__ __launch_bounds__(256) void k_fc0(const float* __restrict__ x,
    const float* __restrict__ w, const float* __restrict__ bias,
    float* __restrict__ h)
{
    int g = blockIdx.x * 256 + threadIdx.x;             // (b,c,sx,sy)
    int b = g >> 18, c = (g >> 12) & 63, sx = (g >> 6) & 63, sy = g & 63;
    const float* xp = x + ((b * 64 + sx) * 64 + sy) * 3;
    float f3 = (float)sx / 63.0f, f4 = (float)sy / 63.0f;
    float acc = bias[c];
    acc = fmaf(xp[0], w[0 * 64 + c], acc);
    acc = fmaf(xp[1], w[1 * 64 + c], acc);
    acc = fmaf(xp[2], w[2 * 64 + c], acc);
    acc = fmaf(f3,    w[3 * 64 + c], acc);
    acc = fmaf(f4,    w[4 * 64 + c], acc);
    h[g] = acc;
}

// ---------------- DWT2 (both axes fused per (b,c)) ----------------
__global__ __launch_bounds__(256) void k_dwt(const float* __restrict__ h,
    float* __restrict__ s)
{
    constexpr float DL[8] = DL_INIT;
    constexpr float DH[8] = DH_INIT;
    __shared__ float xs[4096];
    __shared__ float tlo[2240];
    __shared__ float thi[2240];
    int bc = blockIdx.x, t = threadIdx.x;
    const float* hp = h + bc * 4096;
    #pragma unroll
    for (int k = 0; k < 16; ++k) xs[t + k * 256] = hp[t + k * 256];
    __syncthreads();
    for (int u = t; u < 2240; u += 256) {
        int sx = u / 35, oy = u - sx * 35;
        int y0 = 2 * oy + 1;
        float al = 0.f, ah = 0.f;
        #pragma unroll
        for (int j = 0; j < 8; ++j) {
            int yy = y0 - j;
            yy = (yy < 0) ? (-1 - yy) : yy;
            yy = (yy > 63) ? (127 - yy) : yy;
            float v = xs[sx * 64 + yy];
            al = fmaf(DL[j], v, al);
            ah = fmaf(DH[j], v, ah);
        }
        tlo[u] = al; thi[u] = ah;
    }
    __syncthreads();
    float* s0 = s + bc * SP;
    for (int u = t; u < 1225; u += 256) {
        int ox = u / 35, oy = u - ox * 35;
        int x0 = 2 * ox + 1;
        float a_ll = 0.f, a_lh = 0.f, a_hl = 0.f, a_hh = 0.f;
        #pragma unroll
        for (int j = 0; j < 8; ++j) {
            int xx = x0 - j;
            xx = (xx < 0) ? (-1 - xx) : xx;
            xx = (xx > 63) ? (127 - xx) : xx;
            float vl = tlo[xx * 35 + oy];
            float vh = thi[xx * 35 + oy];
            a_ll = fmaf(DL[j], vl, a_ll);
            a_lh = fmaf(DH[j], vl, a_lh);
            a_hl = fmaf(DL[j], vh, a_hl);
            a_hh = fmaf(DH[j], vh, a_hh);
        }
        s0[u]             = a_ll;
        s0[PLANE + u]     = a_lh;
        s0[2 * PLANE + u] = a_hl;
        s0[3 * PLANE + u] = a_hh;
    }
}

// ---------------- mul2d: out[b][o][p] = sum_i in[b][i][p] * w[i][o][p] ----------------
__global__ __launch_bounds__(128) void k_mul2d(const float* __restrict__ sIn,
    const float* __restrict__ W, float* __restrict__ mOut)
{
    // bijective XCD swizzle over 308 (q=38, r=4)
    int raw = blockIdx.x;
    int xcd = raw & 7, kk = raw >> 3;
    int sid = (xcd < 4) ? (xcd * 39 + kk) : (156 + (xcd - 4) * 38 + kk);
    int tile = sid >> 1, og = sid & 1;
    int z = blockIdx.y;
    int p0 = tile * 8;
    const float* in = sIn + (size_t)z * PLANE;
    const float* w  = W   + (size_t)z * 5017600;
    float* out = mOut + (size_t)z * PLANE;
    int t = threadIdx.x;
    int p = t & 7, wg = t >> 3;
    int oA = og * 32 + wg * 2;
    int pp = min(p0 + p, 1224);
    float a0[32], a1[32];
    #pragma unroll
    for (int b = 0; b < 32; ++b) { a0[b] = 0.f; a1[b] = 0.f; }
    __shared__ float inp[4 * 8 * 34];   // [ii][pl][b pad 34]
    for (int ic = 0; ic < 64; ic += 4) {
        __syncthreads();
        #pragma unroll
        for (int k = 0; k < 8; ++k) {
            int e = t + k * 128;            // e = (b*4+ii)*8 + pl
            int pl = e & 7, ii = (e >> 3) & 3, b = e >> 5;
            int gp = min(p0 + pl, 1224);
            inp[(ii * 8 + pl) * 34 + b] = in[(b * 64 + ic + ii) * SP + gp];
        }
        __syncthreads();
        #pragma unroll
        for (int ii = 0; ii < 4; ++ii) {
            int i = ic + ii;
            float w0 = w[(i * 64 + oA) * 1225 + pp];
            float w1 = w[(i * 64 + oA + 1) * 1225 + pp];
            const float2* ip = reinterpret_cast<const float2*>(&inp[(ii * 8 + p) * 34]);
            #pragma unroll
            for (int bq = 0; bq < 16; ++bq) {
                float2 v = ip[bq];
                a0[bq * 2]     = fmaf(v.x, w0, a0[bq * 2]);
                a1[bq * 2]     = fmaf(v.x, w1, a1[bq * 2]);
                a0[bq * 2 + 1] = fmaf(v.y, w0, a0[bq * 2 + 1]);
                a1[bq * 2 + 1] = fmaf(v.y, w1, a1[bq * 2 + 1]);
            }
        }
    }
    if (p0 + p < 1225) {
        #pragma unroll
        for (int b = 0; b < 32; ++b) {
            out[(b * 64 + oA) * SP + p0 + p]     = a0[b];
            out[(b * 64 + oA + 1) * SP + p0 + p] = a1[b];
        }
    }
}

// ---------------- fused column-synthesis + pointwise conv + row-synthesis + relu ----
// Block = one (b, sx) output row: 64 sy x 64 o. 256 threads.
// Stage A: u[o][g][oy] (g=0: from m-planes 0,1 ; g=1: from planes 2,3) in LDS.
// Stage B: thread = (p2 = sy-pair, og -> 8 o): pconv (h via coalesced global float2,
//          cwt via LDS broadcast) + row synthesis + bias + relu, float2 store.
__global__ __launch_bounds__(256) void k_synth(const float* __restrict__ m,
    const float* __restrict__ h, const float* __restrict__ cw,
    const float* __restrict__ cb, float* __restrict__ hOut)
{
    constexpr float DL[8] = DL_INIT;
    constexpr float DH[8] = DH_INIT;
    __shared__ float u[64 * 2 * 36];     // [o][g][oy pad36] = 18.4 KB
    __shared__ float cwt[4096];          // [i][o] = cw[o][i]
    int t = threadIdx.x;
    int bs = blockIdx.x;
    int b = bs >> 6, sx = bs & 63;
    #pragma unroll
    for (int k = 0; k < 16; ++k) {
        int e = t + k * 256;
        cwt[e] = cw[(e & 63) * 64 + (e >> 6)];
    }
    // Stage A: column synthesis for row n = sx. even sx -> DL[1,3,5,7], odd -> DL[0,2,4,6]
    int q2 = sx & 1, mm2 = sx >> 1;
    float c0 = q2 ? DL[0] : DL[1], c1 = q2 ? DL[2] : DL[3];
    float c2 = q2 ? DL[4] : DL[5], c3 = q2 ? DL[6] : DL[7];
    float d0 = q2 ? DH[0] : DH[1], d1 = q2 ? DH[2] : DH[3];
    float d2 = q2 ? DH[4] : DH[5], d3 = q2 ? DH[6] : DH[7];
    for (int v = t; v < 4480; v += 256) {
        int o = v / 70, rr = v - o * 70;
        int g = rr / 35, oy = rr - g * 35;
        const float* lo = m + (size_t)(g * 2) * PLANE + (b * 64 + o) * SP + mm2 * 35 + oy;
        const float* hi = lo + PLANE;
        float a = c0 * lo[0];
        a = fmaf(c1, lo[35], a);
        a = fmaf(c2, lo[70], a);
        a = fmaf(c3, lo[105], a);
        a = fmaf(d0, hi[0], a);
        a = fmaf(d1, hi[35], a);
        a = fmaf(d2, hi[70], a);
        a = fmaf(d3, hi[105], a);
        u[(o * 2 + g) * 36 + oy] = a;
    }
    __syncthreads();
    // Stage B
    int p2 = t & 31, og = t >> 5;
    int o0 = og * 8;
    float acc0[8], acc1[8];
    #pragma unroll
    for (int k = 0; k < 8; ++k) { acc0[k] = cb[o0 + k]; acc1[k] = acc0[k]; }
    const float* hp = h + (((size_t)b * 64) << 12) + (sx << 6) + p2 * 2;
    for (int i = 0; i < 64; ++i) {
        float2 hv = *reinterpret_cast<const float2*>(&hp[(size_t)i << 12]);
        float4 w0 = *reinterpret_cast<const float4*>(&cwt[i * 64 + o0]);
        float4 w1 = *reinterpret_cast<const float4*>(&cwt[i * 64 + o0 + 4]);
        acc0[0] = fmaf(hv.x, w0.x, acc0[0]); acc1[0] = fmaf(hv.y, w0.x, acc1[0]);
        acc0[1] = fmaf(hv.x, w0.y, acc0[1]); acc1[1] = fmaf(hv.y, w0.y, acc1[1]);
        acc0[2] = fmaf(hv.x, w0.z, acc0[2]); acc1[2] = fmaf(hv.y, w0.z, acc1[2]);
        acc0[3] = fmaf(hv.x, w0.w, acc0[3]); acc1[3] = fmaf(hv.y, w0.w, acc1[3]);
        acc0[4] = fmaf(hv.x, w1.x, acc0[4]); acc1[4] = fmaf(hv.y, w1.x, acc1[4]);
        acc0[5] = fmaf(hv.x, w1.y, acc0[5]); acc1[5] = fmaf(hv.y, w1.y, acc1[5]);
        acc0[6] = fmaf(hv.x, w1.z, acc0[6]); acc1[6] = fmaf(hv.y, w1.z, acc1[6]);
        acc0[7] = fmaf(hv.x, w1.w, acc0[7]); acc1[7] = fmaf(hv.y, w1.w, acc1[7]);
    }
    // row synthesis: even sy (2*p2) uses DL[1,3,5,7]; odd uses DL[0,2,4,6]; mm = p2
    int mm = p2;
    float* op = hOut + (((size_t)b * 64) << 12) + (sx << 6) + p2 * 2;
    #pragma unroll
    for (int k = 0; k < 8; ++k) {
        int o = o0 + k;
        const float* lu = &u[(o * 2) * 36 + mm];
        const float* hu = &u[(o * 2 + 1) * 36 + mm];
        float l0 = lu[0], l1 = lu[1], l2 = lu[2], l3 = lu[3];
        float g0 = hu[0], g1 = hu[1], g2 = hu[2], g3 = hu[3];
        float xe = DL[1] * l0;
        xe = fmaf(DL[3], l1, xe); xe = fmaf(DL[5], l2, xe); xe = fmaf(DL[7], l3, xe);
        xe = fmaf(DH[1], g0, xe); xe = fmaf(DH[3], g1, xe);
        xe = fmaf(DH[5], g2, xe); xe = fmaf(DH[7], g3, xe);
        float xo = DL[0] * l0;
        xo = fmaf(DL[2], l1, xo); xo = fmaf(DL[4], l2, xo); xo = fmaf(DL[6], l3, xo);
        xo = fmaf(DH[0], g0, xo); xo = fmaf(DH[2], g1, xo);
        xo = fmaf(DH[4], g2, xo); xo = fmaf(DH[6], g3, xo);
        float2 r;
        r.x = fmaxf(acc0[k] + xe, 0.f);
        r.y = fmaxf(acc1[k] + xo, 0.f);
        *reinterpret_cast<float2*>(&op[(size_t)o << 12]) = r;
    }
}

// ---------------- fused fc1 + relu + fc2 (+bias), fp32 store, 2 px/thread ----------------
__global__ __launch_bounds__(256) void k_fc_final(const float* __restrict__ h,
    const float* __restrict__ w1, const float* __restrict__ b1,
    const float* __restrict__ w2, const float* __restrict__ b2,
    float* __restrict__ out)
{
    __shared__ float w1t[16384];   // w1t[j][c] = w1[c][j]
    int t = threadIdx.x;
    #pragma unroll
    for (int k = 0; k < 64; ++k) {
        int e = t + k * 256;
        w1t[e] = w1[(e & 63) * 256 + (e >> 6)];
    }
    __syncthreads();
    int g0 = blockIdx.x * 512 + t;
    int b = g0 >> 12, px0 = g0 & 4095, px1 = px0 + 256;
    const float* hp = h + ((size_t)b << 18);
    float ha[64], hb[64];
    #pragma unroll
    for (int c = 0; c < 64; ++c) {
        ha[c] = hp[(c << 12) + px0];
        hb[c] = hp[(c << 12) + px1];
    }
    float o0 = 0.f, o1 = 0.f;
    for (int j = 0; j < 256; ++j) {
        float a0 = b1[j], a1 = a0;
        const float4* wr = reinterpret_cast<const float4*>(&w1t[j << 6]);
        #pragma unroll
        for (int c4 = 0; c4 < 16; ++c4) {
            float4 wv = wr[c4];
            a0 = fmaf(ha[c4 * 4 + 0], wv.x, a0); a1 = fmaf(hb[c4 * 4 + 0], wv.x, a1);
            a0 = fmaf(ha[c4 * 4 + 1], wv.y, a0); a1 = fmaf(hb[c4 * 4 + 1], wv.y, a1);
            a0 = fmaf(ha[c4 * 4 + 2], wv.z, a0); a1 = fmaf(hb[c4 * 4 + 2], wv.z, a1);
            a0 = fmaf(ha[c4 * 4 + 3], wv.w, a0); a1 = fmaf(hb[c4 * 4 + 3], wv.w, a1);
        }
        float f = w2[j];
        o0 = fmaf(fmaxf(a0, 0.f), f, o0);
        o1 = fmaf(fmaxf(a1, 0.f), f, o1);
    }
    float bb = b2[0];
    out[g0]       = o0 + bb;
    out[g0 + 256] = o1 + bb;
}

extern "C" void kernel_launch(void* const* d_in, const int* in_sizes, int n_in,
                              void* d_out, int out_size, void* d_ws, size_t ws_size,
                              hipStream_t stream)
{
    const float* x     = (const float*)d_in[0];
    const float* fc0w  = (const float*)d_in[1];
    const float* fc0b  = (const float*)d_in[2];
    const float* wno   = (const float*)d_in[3];
    const float* convw = (const float*)d_in[4];
    const float* convb = (const float*)d_in[5];
    const float* fc1w  = (const float*)d_in[6];
    const float* fc1b  = (const float*)d_in[7];
    const float* fc2w  = (const float*)d_in[8];
    const float* fc2b  = (const float*)d_in[9];
    (void)in_sizes; (void)n_in; (void)out_size; (void)ws_size;

    float* ws  = (float*)d_ws;
    float* hA  = ws;
    float* hB  = hA + 8388608;
    float* sU  = hB + 8388608;
    float* mB  = sU + 4 * (size_t)PLANE;

    k_fc0<<<32768, 256, 0, stream>>>(x, fc0w, fc0b, hA);

    float* hin = hA;
    float* hout = hB;
    for (int blk = 0; blk < 4; ++blk) {
        k_dwt<<<2048, 256, 0, stream>>>(hin, sU);
        k_mul2d<<<dim3(308, 4), 128, 0, stream>>>(sU, wno + (size_t)blk * 20070400, mB);
        k_synth<<<2048, 256, 0, stream>>>(mB, hin,
                                          convw + blk * 4096, convb + blk * 64, hout);
        float* tmp = hin; hin = hout; hout = tmp;
    }

    k_fc_final<<<256, 256, 0, stream>>>(hin, fc1w, fc1b, fc2w, fc2b,
                                        (float*)d_out);
}